// Round 9
// baseline (464.871 us; speedup 1.0000x reference)
//
#include <hip/hip_runtime.h>
#include <math.h>

#define BB 16
#define TT 1024
#define SS 2048
#define CC 256
#define EE 256
#define NSUB 103        // (SS-1)/STRIDE + 1
#define MAXS 20
#define STRIDE_ 20
#define XCH 32          // t-chunks for xmean partials (TT/XCH = 32 rows each)

static constexpr float RSQRT2  = 0.70710678118654752440f;   // sqrt(0.5)
static constexpr float SQRT_S  = 45.25483399593904f;        // s*sqrt(1/s) = sqrt(2048)
static constexpr float GNORM   = 0.13298076013381093f;      // 1/(sqrt(2*pi)*3)
static constexpr float INV2S2  = 0.055555555555555555f;     // 1/(2*sigma^2)

typedef __attribute__((ext_vector_type(8))) __bf16 bf16x8;
typedef __attribute__((ext_vector_type(4))) float  f32x4;

__device__ __forceinline__ float wave_sum(float v) {
    #pragma unroll
    for (int o = 32; o; o >>= 1) v += __shfl_down(v, o);
    return v;
}
__device__ __forceinline__ float wave_max(float v) {
    #pragma unroll
    for (int o = 32; o; o >>= 1) v = fmaxf(v, __shfl_down(v, o));
    return v;
}
__device__ __forceinline__ unsigned short f2bf(float f) {   // RNE
    unsigned int u = __float_as_uint(f);
    u = (u + 0x7FFFu + ((u >> 16) & 1u)) >> 16;
    return (unsigned short)u;
}
__device__ __forceinline__ float bf2f(unsigned short s) {
    return __uint_as_float(((unsigned int)s) << 16);
}

#define GLD_LDS16(g, l) __builtin_amdgcn_global_load_lds(                      \
    (const __attribute__((address_space(1))) void*)(g),                        \
    (__attribute__((address_space(3))) void*)(l), 16, 0, 0)

// ---------------------------------------------------------------------------
// Prep: both input transposes (blocks 0..4095) + the three fp32->bf16 casts
// (blocks 4096..) in a single launch.
// ---------------------------------------------------------------------------
__global__ __launch_bounds__(256) void k_prep(
    const float* __restrict__ keys, unsigned short* __restrict__ keysT,
    const float* __restrict__ vals, unsigned short* __restrict__ valsT,
    const float* __restrict__ a,  unsigned short* __restrict__ oa, int na,
    const float* __restrict__ b2, unsigned short* __restrict__ ob, int nb,
    const float* __restrict__ c2, unsigned short* __restrict__ oc, int nc)
{
    const int id = blockIdx.x;
    if (id >= 4096) {                       // cast part
        int i = (id - 4096) * 256 + threadIdx.x;
        const float* in; unsigned short* out;
        if (i < na)                { in = a;  out = oa; }
        else if (i < na + nb)      { in = b2; out = ob; i -= na; }
        else if (i < na + nb + nc) { in = c2; out = oc; i -= na + nb; }
        else return;
        const float4 v = reinterpret_cast<const float4*>(in)[i];
        union { unsigned short u[4]; unsigned long long v8; } pk;
        pk.u[0] = f2bf(v.x); pk.u[1] = f2bf(v.y);
        pk.u[2] = f2bf(v.z); pk.u[3] = f2bf(v.w);
        reinterpret_cast<unsigned long long*>(out)[i] = pk.v8;
        return;
    }
    // transpose part: fp32 [Bz][R][Cc] -> bf16 [Bz][Cc][R]
    __shared__ float t[64][65];
    const float* in; unsigned short* out;
    int R, Cc, bx, by, b;
    if (id < 2048) {
        in = keys; out = keysT; R = EE; Cc = SS;
        bx = id & 3; by = (id >> 2) & 31; b = id >> 7;
    } else {
        const int id2 = id - 2048;
        in = vals; out = valsT; R = SS; Cc = EE;
        bx = id2 & 31; by = (id2 >> 5) & 3; b = id2 >> 7;
    }
    const int r0 = bx * 64, c0 = by * 64;
    const float* ip = in + (size_t)b * R * Cc;
    unsigned short* op = out + (size_t)b * R * Cc;
    const int tx = threadIdx.x & 63, ty = threadIdx.x >> 6;  // ty in [0,4)
    #pragma unroll
    for (int i = 0; i < 16; ++i)
        t[ty + 4 * i][tx] = ip[(size_t)(r0 + ty + 4 * i) * Cc + c0 + tx];
    __syncthreads();
    #pragma unroll
    for (int i = 0; i < 16; ++i)
        op[(size_t)(c0 + ty + 4 * i) * R + r0 + tx] = f2bf(t[tx][ty + 4 * i]);
}

// ---------------------------------------------------------------------------
// Unified bf16 MFMA GEMM (R5-proven): BK=64, XOR-swizzled LDS (pre-swizzled
// global source column, linear global_load_lds dest; reads apply the same
// XOR), XCD-chunked bijective blockIdx swizzle. 4 waves, 2x2 wave grid.
// MODE 0: Of = acc*scale
// MODE 1: Of = (acc + bias[n] + add[m,n])*RSQRT2
// MODE 2: Ob = bf16((acc + bias[n] + add[m,n])*RSQRT2)
// MODE 3: Ob = bf16(acc*scale)
// ---------------------------------------------------------------------------
template<int BM, int BN, int MODE>
__global__ __launch_bounds__(256) void k_gemm(
    const unsigned short* __restrict__ Abase,
    const unsigned short* __restrict__ Btbase,
    const float* __restrict__ bias, const float* __restrict__ add,
    float* __restrict__ Obase, unsigned short* __restrict__ Obbase,
    int M, int Nn, int K, float scale)
{
    constexpr int BK = 64;
    constexpr int AR = BM / 32;
    constexpr int BR = BN / 32;
    constexpr int WM = BM / 2, WN = BN / 2;
    constexpr int MI = WM / 16, NJ = WN / 16;

    __shared__ unsigned short As[BM * BK];
    __shared__ unsigned short Bs[BN * BK];

    const int nwg = gridDim.x * gridDim.y * gridDim.z;
    int l = blockIdx.x + gridDim.x * (blockIdx.y + gridDim.y * blockIdx.z);
    if ((nwg & 7) == 0) l = (l & 7) * (nwg >> 3) + (l >> 3);
    const int bx = l % gridDim.x; l /= gridDim.x;
    const int by = l % gridDim.y;
    const int b  = l / gridDim.y;

    const int m0 = bx * BM;
    const int n0 = by * BN;
    const unsigned short* A  = Abase  + (size_t)b * M  * K;
    const unsigned short* Bt = Btbase + (size_t)b * Nn * K;

    const int tid  = threadIdx.x;
    const int w    = tid >> 6;
    const int lane = tid & 63;
    const int wm   = w & 1, wn = w >> 1;

    const int sr  = tid >> 3;
    const int skb = ((tid & 7) << 4) ^ ((sr & 7) << 4);
    const unsigned short* ga[AR];
    const unsigned short* gb[BR];
    #pragma unroll
    for (int p = 0; p < AR; ++p)
        ga[p] = A + (size_t)(m0 + p * 32 + sr) * K + (skb >> 1);
    #pragma unroll
    for (int p = 0; p < BR; ++p)
        gb[p] = Bt + (size_t)(n0 + p * 32 + sr) * K + (skb >> 1);

    const int fr = lane & 15;
    const int qb = (lane >> 4) << 4;

    f32x4 acc[MI][NJ];
    #pragma unroll
    for (int i = 0; i < MI; ++i)
        #pragma unroll
        for (int j = 0; j < NJ; ++j)
            acc[i][j] = (f32x4){0.f, 0.f, 0.f, 0.f};

    for (int k0 = 0; k0 < K; k0 += BK) {
        #pragma unroll
        for (int p = 0; p < AR; ++p) GLD_LDS16(ga[p], As + p * 2048 + w * 512);
        #pragma unroll
        for (int p = 0; p < BR; ++p) GLD_LDS16(gb[p], Bs + p * 2048 + w * 512);
        #pragma unroll
        for (int p = 0; p < AR; ++p) ga[p] += BK;
        #pragma unroll
        for (int p = 0; p < BR; ++p) gb[p] += BK;
        __syncthreads();
        #pragma unroll
        for (int c = 0; c < 2; ++c) {
            bf16x8 af[MI], bf[NJ];
            #pragma unroll
            for (int i = 0; i < MI; ++i) {
                const int row = wm * WM + i * 16 + fr;
                const int byt = row * 128 + ((c * 64 + qb) ^ ((row & 7) << 4));
                af[i] = *reinterpret_cast<const bf16x8*>(
                            reinterpret_cast<const char*>(As) + byt);
            }
            #pragma unroll
            for (int j = 0; j < NJ; ++j) {
                const int row = wn * WN + j * 16 + fr;
                const int byt = row * 128 + ((c * 64 + qb) ^ ((row & 7) << 4));
                bf[j] = *reinterpret_cast<const bf16x8*>(
                            reinterpret_cast<const char*>(Bs) + byt);
            }
            #pragma unroll
            for (int i = 0; i < MI; ++i)
                #pragma unroll
                for (int j = 0; j < NJ; ++j)
                    acc[i][j] = __builtin_amdgcn_mfma_f32_16x16x32_bf16(af[i], bf[j], acc[i][j], 0, 0, 0);
        }
        __syncthreads();
    }

    float* Of = (MODE == 0 || MODE == 1) ? Obase + (size_t)b * M * Nn : nullptr;
    unsigned short* Ob = (MODE == 2 || MODE == 3) ? Obbase + (size_t)b * M * Nn : nullptr;
    const int rb = (lane >> 4) * 4;
    #pragma unroll
    for (int i = 0; i < MI; ++i)
        #pragma unroll
        for (int j = 0; j < NJ; ++j) {
            const int n = n0 + wn * WN + j * 16 + fr;
            #pragma unroll
            for (int r2 = 0; r2 < 4; ++r2) {
                const int m = m0 + wm * WM + i * 16 + rb + r2;
                const size_t idx = (size_t)m * Nn + n;
                if (MODE == 0) {
                    Of[idx] = acc[i][j][r2] * scale;
                } else if (MODE == 1) {
                    Of[idx] = (acc[i][j][r2] + bias[n] + add[idx]) * RSQRT2;
                } else if (MODE == 2) {
                    Ob[idx] = f2bf((acc[i][j][r2] + bias[n] + add[idx]) * RSQRT2);
                } else {
                    Ob[idx] = f2bf(acc[i][j][r2] * scale);
                }
            }
        }
}

// ---------------------------------------------------------------------------
// Fused row-softmax + xmean partials. Block = one 32-row chunk (b, c):
// 8 waves, wave w handles rows [w*4, w*4+4) serially (wave-per-row softmax,
// zero barriers in the row loop), keeping its 32-column-slice partial sums in
// registers. Then a 4-phase LDS accumulation ([2][2048]: buffer w>>2, wave w
// adds segment (ph+w)&3) merges 8 waves, and the block writes part[b][c][:].
// Replaces k_softmax + k_xmean_part (saves the 67 MB attnb re-read).
// Also zeroes klp. grid (XCH, BB), 512 thr.
// ---------------------------------------------------------------------------
__global__ __launch_bounds__(512) void k_softmax_xmean(
    float* __restrict__ attn, unsigned short* __restrict__ attnb,
    float* __restrict__ part, float* __restrict__ klp)
{
    const int c = blockIdx.x, b = blockIdx.y;
    const int tid = threadIdx.x;
    if (c == 0 && b == 0 && tid == 0) klp[0] = 0.0f;
    const int wv = tid >> 6, lane = tid & 63;
    __shared__ float colsum[2][2048];
    for (int i = tid; i < 2048; i += 512) { colsum[0][i] = 0.f; colsum[1][i] = 0.f; }

    float colacc[32];
    #pragma unroll
    for (int i = 0; i < 32; ++i) colacc[i] = 0.f;

    const size_t row0 = (size_t)b * TT + (size_t)c * 32 + wv * 4;
    for (int r = 0; r < 4; ++r) {
        float* p = attn + (row0 + r) * SS;
        unsigned short* pb = attnb + (row0 + r) * SS;
        float v[32];
        #pragma unroll
        for (int sg = 0; sg < 4; ++sg) {
            union { unsigned short u[8]; uint4 q; } ld;
            ld.q = *reinterpret_cast<const uint4*>(&pb[sg * 512 + lane * 8]);
            #pragma unroll
            for (int i = 0; i < 8; ++i) v[sg * 8 + i] = bf2f(ld.u[i]);
        }
        float mx = v[0];
        #pragma unroll
        for (int i = 1; i < 32; ++i) mx = fmaxf(mx, v[i]);
        #pragma unroll
        for (int o = 32; o; o >>= 1) mx = fmaxf(mx, __shfl_xor(mx, o));
        float sum = 0.f;
        #pragma unroll
        for (int i = 0; i < 32; ++i) { v[i] = expf(v[i] - mx); sum += v[i]; }
        #pragma unroll
        for (int o = 32; o; o >>= 1) sum += __shfl_xor(sum, o);
        const float inv = 1.0f / sum;
        #pragma unroll
        for (int sg = 0; sg < 4; ++sg) {
            float4 o0, o1;
            o0.x = v[sg * 8 + 0] * inv; o0.y = v[sg * 8 + 1] * inv;
            o0.z = v[sg * 8 + 2] * inv; o0.w = v[sg * 8 + 3] * inv;
            o1.x = v[sg * 8 + 4] * inv; o1.y = v[sg * 8 + 5] * inv;
            o1.z = v[sg * 8 + 6] * inv; o1.w = v[sg * 8 + 7] * inv;
            *reinterpret_cast<float4*>(&p[sg * 512 + lane * 8])     = o0;
            *reinterpret_cast<float4*>(&p[sg * 512 + lane * 8 + 4]) = o1;
            union { unsigned short u[8]; uint4 q; } pk;
            pk.u[0] = f2bf(o0.x); pk.u[1] = f2bf(o0.y); pk.u[2] = f2bf(o0.z); pk.u[3] = f2bf(o0.w);
            pk.u[4] = f2bf(o1.x); pk.u[5] = f2bf(o1.y); pk.u[6] = f2bf(o1.z); pk.u[7] = f2bf(o1.w);
            *reinterpret_cast<uint4*>(&pb[sg * 512 + lane * 8]) = pk.q;
            colacc[sg * 8 + 0] += o0.x; colacc[sg * 8 + 1] += o0.y;
            colacc[sg * 8 + 2] += o0.z; colacc[sg * 8 + 3] += o0.w;
            colacc[sg * 8 + 4] += o1.x; colacc[sg * 8 + 5] += o1.y;
            colacc[sg * 8 + 6] += o1.z; colacc[sg * 8 + 7] += o1.w;
        }
    }
    __syncthreads();   // colsum zero-init + all waves done with rows
    // 4-phase accumulation: waves 0-3 -> colsum[0], waves 4-7 -> colsum[1];
    // in phase ph, wave w adds segment (ph + w) & 3 (no two waves of the same
    // buffer share a segment within a phase; barriers order the phases).
    #pragma unroll
    for (int ph = 0; ph < 4; ++ph) {
        const int sg = (ph + wv) & 3;
        float* cs = &colsum[wv >> 2][sg * 512 + lane * 8];
        #pragma unroll
        for (int i = 0; i < 8; ++i) cs[i] += colacc[sg * 8 + i];
        __syncthreads();
    }
    float* o = part + ((size_t)b * XCH + c) * SS;
    for (int i = tid; i < 2048; i += 512) o[i] = colsum[0][i] + colsum[1][i];
}

// L[b,i,j] = aa_i*aa_j * dot(ev_i,ev_j)/(|ev_i||ev_j|), rows i*STRIDE of
// enc_values. grid (NSUB, BB), 128 thr.
__global__ __launch_bounds__(128) void k_L_direct(const float* __restrict__ ev,
                                                  const float* __restrict__ part,
                                                  float* __restrict__ Lm)
{
    const int i = blockIdx.x, b = blockIdx.y;
    const int tid = threadIdx.x;
    __shared__ float evi[EE];
    __shared__ float aaS[NSUB];
    __shared__ float w[2];
    const float* rowi = ev + ((size_t)b * SS + (size_t)i * STRIDE_) * EE;
    const float v0 = rowi[tid], v1 = rowi[tid + 128];
    evi[tid] = v0; evi[tid + 128] = v1;
    const float r = wave_sum(v0 * v0 + v1 * v1);
    if ((tid & 63) == 0) w[tid >> 6] = r;
    if (tid < NSUB) {
        float s = 0.f;
        #pragma unroll 8
        for (int c2 = 0; c2 < XCH; ++c2)
            s += part[((size_t)b * XCH + c2) * SS + tid * STRIDE_];
        aaS[tid] = s * (1.0f / TT);
    }
    __syncthreads();
    const float nrmi = sqrtf(w[0] + w[1]);
    const float ai = aaS[i];
    for (int j = tid; j < NSUB; j += 128) {
        const float* rj = ev + ((size_t)b * SS + (size_t)j * STRIDE_) * EE;
        float d = 0.f, n2 = 0.f;
        #pragma unroll 4
        for (int e = 0; e < EE; e += 4) {
            const float4 a4 = *reinterpret_cast<const float4*>(&evi[e]);
            const float4 b4 = *reinterpret_cast<const float4*>(&rj[e]);
            d  += a4.x * b4.x + a4.y * b4.y + a4.z * b4.z + a4.w * b4.w;
            n2 += b4.x * b4.x + b4.y * b4.y + b4.z * b4.z + b4.w * b4.w;
        }
        Lm[((size_t)b * NSUB + i) * NSUB + j] = d * ai * aaS[j] / (nrmi * sqrtf(n2));
    }
}

// Greedy MAP DPP (Cholesky, SINGLE WAVE, barrier-free) + dist + KL.
__global__ __launch_bounds__(256) void k_bfgm_kl(const float* __restrict__ Lm,
                                                 const float* __restrict__ part,
                                                 float* __restrict__ outkl)
{
    const int b = blockIdx.x;
    const int tid = threadIdx.x;
    const float* L = Lm + (size_t)b * NSUB * NSUB;
    __shared__ float CmL[128 * 21];
    __shared__ float musS[MAXS];
    __shared__ float w[4];

    // prefetch xm (independent of Cholesky; overlaps wave-0 serial work)
    float xm[8];
    #pragma unroll
    for (int i = 0; i < 8; ++i) {
        float s = 0.f;
        #pragma unroll 8
        for (int c2 = 0; c2 < XCH; ++c2)
            s += part[((size_t)b * XCH + c2) * SS + tid + (i << 8)];
        xm[i] = s * (1.0f / TT);
    }

    if (tid < 64) {
        const int i0 = tid, i1 = tid + 64;
        const bool a1 = (i1 < NSUB);
        float D0 = L[(size_t)i0 * NSUB + i0];
        float D1 = a1 ? L[(size_t)i1 * NSUB + i1] : 0.0f;
        float m0 = 1.0f, m1 = a1 ? 1.0f : 0.0f;
        #pragma unroll
        for (int k = 0; k < MAXS; ++k) { CmL[i0 * 21 + k] = 0.0f; CmL[i1 * 21 + k] = 0.0f; }
        #pragma unroll 1
        for (int t = 0; t < MAXS; ++t) {
            float k0 = logf(D0 * m0); if (isnan(k0)) k0 = INFINITY;
            float k1 = a1 ? logf(D1 * m1) : -INFINITY; if (isnan(k1)) k1 = INFINITY;
            float v = k0; int idx = i0;
            if (k1 > v) { v = k1; idx = i1; }
            #pragma unroll
            for (int o = 32; o; o >>= 1) {
                const float ov = __shfl_down(v, o);
                const int   oi = __shfl_down(idx, o);
                if (ov > v || (ov == v && oi < idx)) { v = ov; idx = oi; }
            }
            const int J = __shfl(idx, 0);
            if (J == i0) m0 = 0.0f;
            if (J == i1) m1 = 0.0f;
            if (tid == 0) musS[t] = (float)J;
            if (t == MAXS - 1) break;
            const float Dsel = (J >= 64) ? D1 : D0;
            const float dj = __shfl(Dsel, J & 63);
            const float Lj0 = L[(size_t)J * NSUB + i0];
            const float Lj1 = a1 ? L[(size_t)J * NSUB + i1] : 0.0f;
            float cd0 = 0.0f, cd1 = 0.0f;
            for (int k = 1; k <= t; ++k) {
                const float cjk = CmL[J * 21 + k];
                cd0 += CmL[i0 * 21 + k] * cjk;
                cd1 += CmL[i1 * 21 + k] * cjk;
            }
            const float e0 = (Lj0 - cd0) / dj * m0;
            const float e1 = a1 ? (Lj1 - cd1) / dj * m1 : 0.0f;
            CmL[i0 * 21 + t + 1] = e0;
            CmL[i1 * 21 + t + 1] = e1;
            __threadfence_block();
            D0 -= e0 * e0;
            D1 -= e1 * e1;
        }
    }
    __syncthreads();

    float g[8];
    float mx = -INFINITY;
    #pragma unroll
    for (int i = 0; i < 8; ++i) {
        const float s = (float)(tid + (i << 8));
        float acc = 0.f;
        #pragma unroll
        for (int m = 0; m < MAXS; ++m) { const float z = s - musS[m]; acc += expf(-(z * z) * INV2S2); }
        g[i] = acc * GNORM;
        mx = fmaxf(mx, g[i]);
    }
    float wm = wave_max(mx);
    if ((tid & 63) == 0) w[tid >> 6] = wm;
    __syncthreads();
    const float m = fmaxf(fmaxf(w[0], w[1]), fmaxf(w[2], w[3]));
    float sum = 0.f;
    #pragma unroll
    for (int i = 0; i < 8; ++i) { g[i] = expf(g[i] - m); sum += g[i]; }
    __syncthreads();
    float wsv = wave_sum(sum);
    if ((tid & 63) == 0) w[tid >> 6] = wsv;
    __syncthreads();
    const float inv = 1.0f / (w[0] + w[1] + w[2] + w[3]);
    float acc2 = 0.f;
    #pragma unroll
    for (int i = 0; i < 8; ++i)
        acc2 += xm[i] * (logf(xm[i]) - g[i] * inv);
    __syncthreads();
    float wp = wave_sum(acc2);
    if ((tid & 63) == 0) w[tid >> 6] = wp;
    __syncthreads();
    if (tid == 0) atomicAdd(outkl, -(w[0] + w[1] + w[2] + w[3]));
}

extern "C" void kernel_launch(void* const* d_in, const int* in_sizes, int n_in,
                              void* d_out, int out_size, void* d_ws, size_t ws_size,
                              hipStream_t stream)
{
    const float* x     = (const float*)d_in[0];   // (B,T,C)
    const float* te    = (const float*)d_in[1];   // (B,T,E)
    const float* keys  = (const float*)d_in[2];   // (B,E,S)
    const float* vals  = (const float*)d_in[3];   // (B,S,E)
    const float* W_in  = (const float*)d_in[4];   // (E,C)
    const float* b_in  = (const float*)d_in[5];   // (E)
    const float* W_out = (const float*)d_in[6];   // (C,E)
    const float* b_out = (const float*)d_in[7];   // (C)

    float* outp = (float*)d_out;                       // (B,T,C)
    float* attn = outp + (size_t)BB * TT * CC;         // (B,T,S) fp32
    float* klp  = attn + (size_t)BB * TT * SS;         // scalar

    // workspace
    unsigned short* X       = (unsigned short*)d_ws;
    unsigned short* x_bf    = X;                                       // B*T*C
    unsigned short* Win_bf  = x_bf   + (size_t)BB * TT * CC;           // E*C
    unsigned short* Wout_bf = Win_bf + (size_t)EE * CC;                // C*E
    unsigned short* h_bf    = Wout_bf+ (size_t)CC * EE;                // B*T*E
    unsigned short* keysT   = h_bf   + (size_t)BB * TT * EE;           // B*S*E
    unsigned short* valsT   = keysT  + (size_t)BB * SS * EE;           // B*E*S
    unsigned short* attnb   = valsT  + (size_t)BB * EE * SS;           // B*T*S (scores, then attn)
    unsigned short* mid_bf  = attnb  + (size_t)BB * TT * SS;           // B*T*E
    float* fws   = (float*)(mid_bf + (size_t)BB * TT * EE + 8);
    float* part  = fws;                                  // (B,XCH,S)
    float* Lm    = part  + (size_t)BB * XCH * SS;        // (B,N,N)

    // 0) prep: transposes + casts in one launch
    {
        const int na = BB * TT * CC / 4, nb = EE * CC / 4, nc = CC * EE / 4;
        const int blocks = 4096 + (na + nb + nc + 255) / 256;
        k_prep<<<blocks, 256, 0, stream>>>(keys, keysT, vals, valsT,
                                           x, x_bf, na, W_in, Win_bf, nb, W_out, Wout_bf, nc);
    }
    // 1) h_bf = bf16((x @ W_in^T + b_in + te) * sqrt(.5))   [64x64, 1024 blocks]
    k_gemm<64, 64, 2><<<dim3(256, 4, 1), 256, 0, stream>>>(
        x_bf, Win_bf, b_in, te, nullptr, h_bf, BB * TT, CC, CC, 1.0f);
    // 2) scores (bf16) -> attnb   [128x128, 2048 blocks]
    k_gemm<128, 128, 3><<<dim3(8, 16, BB), 256, 0, stream>>>(
        h_bf, keysT, nullptr, nullptr, nullptr, attnb, TT, SS, EE, 1.0f);
    // 3) fused softmax + xmean partials (also zeroes klp)   [512 blocks]
    k_softmax_xmean<<<dim3(XCH, BB), 512, 0, stream>>>(attn, attnb, part, klp);
    // 4) DPP chain
    k_L_direct<<<dim3(NSUB, BB), 128, 0, stream>>>(vals, part, Lm);
    k_bfgm_kl<<<BB, 256, 0, stream>>>(Lm, part, klp);
    // 5) mid_bf = bf16((attn @ enc_values) * sqrt(S))   [32x128, 1024 blocks]
    k_gemm<32, 128, 3><<<dim3(32, 2, BB), 256, 0, stream>>>(
        attnb, valsT, nullptr, nullptr, nullptr, mid_bf, TT, EE, SS, SQRT_S);
    // 6) out = (mid @ W_out^T + b_out + x) * sqrt(.5)   [64x64, 1024 blocks]
    k_gemm<64, 64, 1><<<dim3(256, 4, 1), 256, 0, stream>>>(
        mid_bf, Wout_bf, b_out, x, outp, nullptr, BB * TT, CC, CC, 1.0f);
}